// Round 3
// baseline (1309.562 us; speedup 1.0000x reference)
//
#include <hip/hip_runtime.h>
#include <hip/hip_bf16.h>

#define N_NODES 10000
#define N_EDGES 320000
#define D 128
#define H 512

typedef __bf16 bf16x8 __attribute__((ext_vector_type(8)));
typedef float f32x4 __attribute__((ext_vector_type(4)));
typedef unsigned short u16x8 __attribute__((ext_vector_type(8)));

__device__ __forceinline__ unsigned short f2bf(float f) {
    union { float f; unsigned u; } v; v.f = f;
    unsigned r = v.u + 0x7fffu + ((v.u >> 16) & 1u);
    return (unsigned short)(r >> 16);
}

// ---------------- fused precompute: cast x, zero agg, swizzle 4 weights ----------------
// swizzle layout: [(kt*(N/16)+nt)*64 + lane]*8 bf16, elem j = W[kt*32+(lane>>4)*8+j][nt*16+(lane&15)]
__device__ __forceinline__ void swz(const float* __restrict__ W, unsigned short* __restrict__ out,
                                    int K, int Nn, int t) {
    int lane = t & 63;
    int tile = t >> 6;
    int ntiles = Nn >> 4;
    int nt = tile % ntiles;
    int kt = tile / ntiles;
    int k0 = kt * 32 + (lane >> 4) * 8;
    int n  = nt * 16 + (lane & 15);
    unsigned short tmp[8];
#pragma unroll
    for (int j = 0; j < 8; ++j) tmp[j] = f2bf(W[(size_t)(k0 + j) * Nn + n]);
    ushort4* dst = reinterpret_cast<ushort4*>(out + (size_t)t * 8);
    dst[0] = *reinterpret_cast<ushort4*>(&tmp[0]);
    dst[1] = *reinterpret_cast<ushort4*>(&tmp[4]);
}

__global__ __launch_bounds__(256) void precompute_kernel(
    const float* __restrict__ x, unsigned short* __restrict__ xb,
    const float* __restrict__ We1, unsigned short* __restrict__ We1s,
    const float* __restrict__ We2, unsigned short* __restrict__ We2s,
    const float* __restrict__ Wn1, unsigned short* __restrict__ Wn1s,
    const float* __restrict__ Wn2, unsigned short* __restrict__ Wn2s,
    float* __restrict__ agg)
{
    int b = blockIdx.x, tid = threadIdx.x;
    if (b < 1250) {                       // cast x -> bf16, 320000 ushort4
        int t = b * 256 + tid;
        float4 v = reinterpret_cast<const float4*>(x)[t];
        ushort4 o;
        o.x = f2bf(v.x); o.y = f2bf(v.y); o.z = f2bf(v.z); o.w = f2bf(v.w);
        reinterpret_cast<ushort4*>(xb)[t] = o;
    } else if (b < 2500) {                // zero agg, 320000 float4
        int t = (b - 1250) * 256 + tid;
        reinterpret_cast<float4*>(agg)[t] = (float4){0.f, 0.f, 0.f, 0.f};
    } else if (b < 2596) {                // We1 384x512 -> 96 blocks
        swz(We1, We1s, 384, 512, (b - 2500) * 256 + tid);
    } else if (b < 2628) {                // We2 512x128 -> 32 blocks
        swz(We2, We2s, 512, 128, (b - 2596) * 256 + tid);
    } else if (b < 2692) {                // Wn1 256x512 -> 64 blocks
        swz(Wn1, Wn1s, 256, 512, (b - 2628) * 256 + tid);
    } else {                              // Wn2 512x128 -> 32 blocks
        swz(Wn2, Wn2s, 512, 128, (b - 2692) * 256 + tid);
    }
}

// ---------------- fused edge MLP + scatter ----------------
// 64 edges/block, 4 waves. NO LDS A-staging: MFMA A-fragments loaded directly
// from global (xb gathers for segs 0/1, edge_attr fp32->bf16 in-register for
// seg 2). LDS = sH chunk only (64 x 136 bf16 = 17.4 KB) -> occupancy is
// VGPR-limited (~3 blocks/CU) instead of LDS-limited (2).
// Chunked like R1 (measured faster than monolithic): 4 chunks x 128 H-cols,
// acc1 = 2 ntiles x 4 mtiles = 32 VGPRs.
__global__ __launch_bounds__(256, 3) void edge_mlp_kernel(
    const unsigned short* __restrict__ xb,
    const int* __restrict__ eidx,
    const float* __restrict__ edge_attr,
    const unsigned short* __restrict__ We1s,
    const float* __restrict__ be1,
    const unsigned short* __restrict__ We2s,
    const float* __restrict__ be2,
    float* __restrict__ out_edges,
    float* __restrict__ agg)
{
    __shared__ unsigned short sH[64 * 136];   // 17,408 B

    const int tid = threadIdx.x;
    const int wave = tid >> 6, lane = tid & 63;
    const int l15 = lane & 15, quad = lane >> 4;
    const int q8 = quad * 8;
    const int e0 = blockIdx.x * 64;

    // gather indices: lane needs sender/receiver node for rows mt*16+l15
    int nodeS[4], nodeR[4];
#pragma unroll
    for (int mt = 0; mt < 4; ++mt) {
        nodeS[mt] = eidx[e0 + mt * 16 + l15];
        nodeR[mt] = eidx[N_EDGES + e0 + mt * 16 + l15];
    }

    f32x4 acc2[2][4];
#pragma unroll
    for (int nn = 0; nn < 2; ++nn)
#pragma unroll
        for (int mt = 0; mt < 4; ++mt) acc2[nn][mt] = (f32x4){0.f, 0.f, 0.f, 0.f};

#pragma unroll 1
    for (int h = 0; h < 4; ++h) {
        // ---- GEMM1 chunk: [64,384] @ We1[:, h*128 .. h*128+127] ----
        f32x4 acc1[2][4];
#pragma unroll
        for (int nn = 0; nn < 2; ++nn)
#pragma unroll
            for (int mt = 0; mt < 4; ++mt) acc1[nn][mt] = (f32x4){0.f, 0.f, 0.f, 0.f};

#pragma unroll
        for (int kt = 0; kt < 12; ++kt) {
            const int seg = kt >> 2;               // 0: x[s], 1: x[r], 2: edge_attr
            const int col = (kt & 3) * 32 + q8;    // within-segment k offset
            bf16x8 a[4];
            if (seg == 0) {
#pragma unroll
                for (int mt = 0; mt < 4; ++mt)
                    a[mt] = *reinterpret_cast<const bf16x8*>(&xb[(size_t)nodeS[mt] * 128 + col]);
            } else if (seg == 1) {
#pragma unroll
                for (int mt = 0; mt < 4; ++mt)
                    a[mt] = *reinterpret_cast<const bf16x8*>(&xb[(size_t)nodeR[mt] * 128 + col]);
            } else {
#pragma unroll
                for (int mt = 0; mt < 4; ++mt) {
                    const float4* s = reinterpret_cast<const float4*>(
                        &edge_attr[(size_t)(e0 + mt * 16 + l15) * 128 + col]);
                    float4 v0 = s[0], v1 = s[1];
                    u16x8 o;
                    o[0] = f2bf(v0.x); o[1] = f2bf(v0.y); o[2] = f2bf(v0.z); o[3] = f2bf(v0.w);
                    o[4] = f2bf(v1.x); o[5] = f2bf(v1.y); o[6] = f2bf(v1.z); o[7] = f2bf(v1.w);
                    a[mt] = *reinterpret_cast<bf16x8*>(&o);
                }
            }
#pragma unroll
            for (int nn = 0; nn < 2; ++nn) {
                bf16x8 b = *reinterpret_cast<const bf16x8*>(
                    &We1s[(((size_t)kt * 32 + h * 8 + wave * 2 + nn) * 64 + lane) * 8]);
#pragma unroll
                for (int mt = 0; mt < 4; ++mt)
                    acc1[nn][mt] = __builtin_amdgcn_mfma_f32_16x16x32_bf16(a[mt], b, acc1[nn][mt], 0, 0, 0);
            }
        }

        __syncthreads();   // previous chunk's GEMM2 reads of sH are done
        // ---- hidden chunk = relu(acc1 + be1) -> bf16 sH (C-layout -> A-layout) ----
#pragma unroll
        for (int nn = 0; nn < 2; ++nn) {
            int cc = (wave * 2 + nn) * 16 + l15;
            float bias = be1[h * 128 + cc];
#pragma unroll
            for (int mt = 0; mt < 4; ++mt)
#pragma unroll
                for (int r = 0; r < 4; ++r) {
                    float v = acc1[nn][mt][r] + bias;
                    v = v > 0.f ? v : 0.f;
                    int row = mt * 16 + quad * 4 + r;
                    sH[row * 136 + cc] = f2bf(v);
                }
        }
        __syncthreads();

        // ---- GEMM2 partial: hidden chunk [64,128] @ We2[h*128.., :] ----
#pragma unroll
        for (int kt2 = 0; kt2 < 4; ++kt2) {
            bf16x8 a[4];
#pragma unroll
            for (int mt = 0; mt < 4; ++mt)
                a[mt] = *reinterpret_cast<const bf16x8*>(&sH[(mt * 16 + l15) * 136 + kt2 * 32 + q8]);
#pragma unroll
            for (int nn = 0; nn < 2; ++nn) {
                bf16x8 b = *reinterpret_cast<const bf16x8*>(
                    &We2s[(((size_t)(h * 4 + kt2) * 8 + wave * 2 + nn) * 64 + lane) * 8]);
#pragma unroll
                for (int mt = 0; mt < 4; ++mt)
                    acc2[nn][mt] = __builtin_amdgcn_mfma_f32_16x16x32_bf16(a[mt], b, acc2[nn][mt], 0, 0, 0);
            }
        }
    }

    // ---- epilogue: edge output + atomic scatter ----
    float bias2[2] = { be2[wave * 32 + l15], be2[wave * 32 + 16 + l15] };
#pragma unroll
    for (int mt = 0; mt < 4; ++mt) {
#pragma unroll
        for (int r = 0; r < 4; ++r) {
            int row = mt * 16 + quad * 4 + r;
            int e = e0 + row;
            int recv = eidx[N_EDGES + e];
#pragma unroll
            for (int nn = 0; nn < 2; ++nn) {
                int cc = wave * 32 + nn * 16 + l15;
                float v = acc2[nn][mt][r] + bias2[nn];
                out_edges[(size_t)e * 128 + cc] = v;
                atomicAdd(&agg[(size_t)recv * 128 + cc], v);
            }
        }
    }
}

// ---------------- fused node MLP ----------------
// Same structure: A-frags direct from global (xb for k<128, agg fp32 for k>=128).
__global__ __launch_bounds__(256, 3) void node_mlp_kernel(
    const unsigned short* __restrict__ xb,
    const float* __restrict__ agg,
    const unsigned short* __restrict__ Wn1s,
    const float* __restrict__ bn1,
    const unsigned short* __restrict__ Wn2s,
    const float* __restrict__ bn2,
    float* __restrict__ out_nodes)
{
    __shared__ unsigned short sH[64 * 136];

    const int tid = threadIdx.x;
    const int wave = tid >> 6, lane = tid & 63;
    const int l15 = lane & 15, quad = lane >> 4;
    const int q8 = quad * 8;
    const int n0 = blockIdx.x * 64;

    int nrow[4];
#pragma unroll
    for (int mt = 0; mt < 4; ++mt) {
        int n = n0 + mt * 16 + l15;
        nrow[mt] = n < N_NODES ? n : N_NODES - 1;   // clamp; OOB rows masked at store
    }

    f32x4 acc2[2][4];
#pragma unroll
    for (int nn = 0; nn < 2; ++nn)
#pragma unroll
        for (int mt = 0; mt < 4; ++mt) acc2[nn][mt] = (f32x4){0.f, 0.f, 0.f, 0.f};

#pragma unroll 1
    for (int h = 0; h < 4; ++h) {
        f32x4 acc1[2][4];
#pragma unroll
        for (int nn = 0; nn < 2; ++nn)
#pragma unroll
            for (int mt = 0; mt < 4; ++mt) acc1[nn][mt] = (f32x4){0.f, 0.f, 0.f, 0.f};

#pragma unroll
        for (int kt = 0; kt < 8; ++kt) {           // K = 256
            const int seg = kt >> 2;               // 0: x, 1: agg
            const int col = (kt & 3) * 32 + q8;
            bf16x8 a[4];
            if (seg == 0) {
#pragma unroll
                for (int mt = 0; mt < 4; ++mt)
                    a[mt] = *reinterpret_cast<const bf16x8*>(&xb[(size_t)nrow[mt] * 128 + col]);
            } else {
#pragma unroll
                for (int mt = 0; mt < 4; ++mt) {
                    const float4* s = reinterpret_cast<const float4*>(
                        &agg[(size_t)nrow[mt] * 128 + col]);
                    float4 v0 = s[0], v1 = s[1];
                    u16x8 o;
                    o[0] = f2bf(v0.x); o[1] = f2bf(v0.y); o[2] = f2bf(v0.z); o[3] = f2bf(v0.w);
                    o[4] = f2bf(v1.x); o[5] = f2bf(v1.y); o[6] = f2bf(v1.z); o[7] = f2bf(v1.w);
                    a[mt] = *reinterpret_cast<bf16x8*>(&o);
                }
            }
#pragma unroll
            for (int nn = 0; nn < 2; ++nn) {
                bf16x8 b = *reinterpret_cast<const bf16x8*>(
                    &Wn1s[(((size_t)kt * 32 + h * 8 + wave * 2 + nn) * 64 + lane) * 8]);
#pragma unroll
                for (int mt = 0; mt < 4; ++mt)
                    acc1[nn][mt] = __builtin_amdgcn_mfma_f32_16x16x32_bf16(a[mt], b, acc1[nn][mt], 0, 0, 0);
            }
        }

        __syncthreads();
#pragma unroll
        for (int nn = 0; nn < 2; ++nn) {
            int cc = (wave * 2 + nn) * 16 + l15;
            float bias = bn1[h * 128 + cc];
#pragma unroll
            for (int mt = 0; mt < 4; ++mt)
#pragma unroll
                for (int r = 0; r < 4; ++r) {
                    float v = acc1[nn][mt][r] + bias;
                    v = v > 0.f ? v : 0.f;
                    int row = mt * 16 + quad * 4 + r;
                    sH[row * 136 + cc] = f2bf(v);
                }
        }
        __syncthreads();

#pragma unroll
        for (int kt2 = 0; kt2 < 4; ++kt2) {
            bf16x8 a[4];
#pragma unroll
            for (int mt = 0; mt < 4; ++mt)
                a[mt] = *reinterpret_cast<const bf16x8*>(&sH[(mt * 16 + l15) * 136 + kt2 * 32 + q8]);
#pragma unroll
            for (int nn = 0; nn < 2; ++nn) {
                bf16x8 b = *reinterpret_cast<const bf16x8*>(
                    &Wn2s[(((size_t)(h * 4 + kt2) * 8 + wave * 2 + nn) * 64 + lane) * 8]);
#pragma unroll
                for (int mt = 0; mt < 4; ++mt)
                    acc2[nn][mt] = __builtin_amdgcn_mfma_f32_16x16x32_bf16(a[mt], b, acc2[nn][mt], 0, 0, 0);
            }
        }
    }

    float bias2[2] = { bn2[wave * 32 + l15], bn2[wave * 32 + 16 + l15] };
#pragma unroll
    for (int mt = 0; mt < 4; ++mt) {
#pragma unroll
        for (int r = 0; r < 4; ++r) {
            int row = mt * 16 + quad * 4 + r;
            int node = n0 + row;
            if (node < N_NODES) {
#pragma unroll
                for (int nn = 0; nn < 2; ++nn) {
                    int cc = wave * 32 + nn * 16 + l15;
                    out_nodes[(size_t)node * 128 + cc] = acc2[nn][mt][r] + bias2[nn];
                }
            }
        }
    }
}

extern "C" void kernel_launch(void* const* d_in, const int* in_sizes, int n_in,
                              void* d_out, int out_size, void* d_ws, size_t ws_size,
                              hipStream_t stream) {
    const float* x         = (const float*)d_in[0];
    const int*   eidx      = (const int*)d_in[1];
    const float* edge_attr = (const float*)d_in[2];
    const float* We1       = (const float*)d_in[3];
    const float* be1       = (const float*)d_in[4];
    const float* We2       = (const float*)d_in[5];
    const float* be2       = (const float*)d_in[6];
    const float* Wn1       = (const float*)d_in[7];
    const float* bn1       = (const float*)d_in[8];
    const float* Wn2       = (const float*)d_in[9];
    const float* bn2       = (const float*)d_in[10];
    float* out = (float*)d_out;

    char* ws = (char*)d_ws;
    size_t off = 0;
    auto alloc = [&](size_t bytes) {
        void* p = ws + off;
        off += (bytes + 255) & ~(size_t)255;
        return p;
    };
    unsigned short* xb   = (unsigned short*)alloc((size_t)N_NODES * D * 2);
    unsigned short* We1s = (unsigned short*)alloc((size_t)384 * 512 * 2);
    unsigned short* We2s = (unsigned short*)alloc((size_t)512 * 128 * 2);
    unsigned short* Wn1s = (unsigned short*)alloc((size_t)256 * 512 * 2);
    unsigned short* Wn2s = (unsigned short*)alloc((size_t)512 * 128 * 2);
    float*          agg  = (float*)alloc((size_t)N_NODES * D * 4);

    precompute_kernel<<<2724, 256, 0, stream>>>(x, xb, We1, We1s, We2, We2s,
                                                Wn1, Wn1s, Wn2, Wn2s, agg);
    edge_mlp_kernel<<<N_EDGES / 64, 256, 0, stream>>>(
        xb, eidx, edge_attr, We1s, be1, We2s, be2, out + (size_t)N_NODES * D, agg);
    node_mlp_kernel<<<(N_NODES + 63) / 64, 256, 0, stream>>>(
        xb, agg, Wn1s, bn1, Wn2s, bn2, out);
}